// Round 4
// baseline (553.360 us; speedup 1.0000x reference)
//
#include <hip/hip_runtime.h>
#include <hip/hip_bf16.h>
#include <math.h>

// Shapes: B=128, C=200, A=312 (pad 320), D=2048, H=1600 (pad 1664), M=B*C=25600
#define BB 128
#define CC 200
#define AA 312
#define AAP 320
#define DD 2048
#define HH 1600
#define HHP 1664
#define MM 25600
#define NKT 26  // K-tiles (BK=64) for gemm_cls: 1664/64

typedef __attribute__((ext_vector_type(8))) short bf16x8;
typedef __attribute__((ext_vector_type(4))) float f32x4;

__device__ __forceinline__ unsigned short f2bf(float f) {
  union { float f; unsigned int u; } v; v.f = f;
  unsigned int u = v.u;
  unsigned int r = (u + 0x7fffu + ((u >> 16) & 1u)) >> 16;
  return (unsigned short)r;
}

__device__ __forceinline__ void gload_lds16(const void* g, void* l) {
  __builtin_amdgcn_global_load_lds(
      (const __attribute__((address_space(1))) unsigned int*)g,
      (__attribute__((address_space(3))) unsigned int*)l, 16, 0, 0);
}

// ---------------- kernel 1: row l2norm of x_in -> xf (fp32) ----------------
__global__ void k_norm(const float* __restrict__ x_in, float* __restrict__ xf) {
  int b = blockIdx.x;
  int t = threadIdx.x;
  const float4* xi = (const float4*)(x_in + (size_t)b * DD);
  float4* xo = (float4*)(xf + (size_t)b * DD);
  float4 v0 = xi[t], v1 = xi[t + 256];
  float s = v0.x*v0.x + v0.y*v0.y + v0.z*v0.z + v0.w*v0.w
          + v1.x*v1.x + v1.y*v1.y + v1.z*v1.z + v1.w*v1.w;
  for (int off = 32; off; off >>= 1) s += __shfl_xor(s, off, 64);
  __shared__ float wsum[4];
  if ((t & 63) == 0) wsum[t >> 6] = s;
  __syncthreads();
  float tot = wsum[0] + wsum[1] + wsum[2] + wsum[3];
  float sc = 1.f / fmaxf(sqrtf(tot), 1e-12f);
  v0.x *= sc; v0.y *= sc; v0.z *= sc; v0.w *= sc;
  v1.x *= sc; v1.y *= sc; v1.z *= sc; v1.w *= sc;
  xo[t] = v0; xo[t + 256] = v1;
}

// ---------------- kernel 2: att = 1 + softmax(relu(xf@Wg^T+bg)/5) ----------
__global__ void k_attn(const float* __restrict__ xf, const float* __restrict__ Wg,
                       const float* __restrict__ bg, float* __restrict__ attp) {
  int b = blockIdx.x;
  int t = threadIdx.x, wv = t >> 6, ln = t & 63;
  __shared__ float xs[DD];
  __shared__ float sa[AA];
  for (int i = t; i < DD / 4; i += 256)
    ((float4*)xs)[i] = ((const float4*)(xf + (size_t)b * DD))[i];
  __syncthreads();
  for (int a = wv; a < AA; a += 4) {
    const float4* wrow = (const float4*)(Wg + (size_t)a * DD);
    float acc = 0.f;
#pragma unroll
    for (int j = 0; j < 8; j++) {
      float4 w = wrow[j * 64 + ln];
      float4 xv = ((const float4*)xs)[j * 64 + ln];
      acc += w.x * xv.x + w.y * xv.y + w.z * xv.z + w.w * xv.w;
    }
    for (int off = 32; off; off >>= 1) acc += __shfl_xor(acc, off, 64);
    if (ln == 0) sa[a] = fmaxf(acc + bg[a], 0.f) * 0.2f;  // /TMP, TMP=5
  }
  __syncthreads();
  if (wv == 0) {
    float mx = -1e30f;
    for (int i = ln; i < AA; i += 64) mx = fmaxf(mx, sa[i]);
    for (int off = 32; off; off >>= 1) mx = fmaxf(mx, __shfl_xor(mx, off, 64));
    float ev[5]; float sm = 0.f;
#pragma unroll
    for (int k = 0; k < 5; k++) {
      int i = ln + k * 64;
      ev[k] = (i < AA) ? expf(sa[i] - mx) : 0.f;
      sm += ev[k];
    }
    for (int off = 32; off; off >>= 1) sm += __shfl_xor(sm, off, 64);
    float inv = 1.f / sm;
#pragma unroll
    for (int k = 0; k < 5; k++) {
      int i = ln + k * 64;
      if (i < AA) attp[(size_t)b * AA + i] = 1.f + ev[k] * inv;
    }
  }
}

// ---------------- kernel 3: comb[m][a] = att'[b][a]*AttM[c][a] (bf16, K-pad) -
__global__ void k_comb(const float* __restrict__ attp, const float* __restrict__ AttM,
                       unsigned short* __restrict__ comb) {
  int m = blockIdx.x;
  int a = threadIdx.x;
  int b = m / CC, c = m % CC;
  unsigned short v = 0;
  if (a < AA) v = f2bf(attp[(size_t)b * AA + a] * AttM[(size_t)c * AA + a]);
  comb[(size_t)m * AAP + a] = v;
}

// ---------------- weight casts (padded, zero-filled) ------------------------
__global__ void k_cast_w1(const float* __restrict__ W1, unsigned short* __restrict__ W1b) {
  int i = blockIdx.x * 256 + threadIdx.x;
  if (i >= HHP * AAP) return;
  int r = i / AAP, c = i % AAP;
  W1b[i] = (r < HH && c < AA) ? f2bf(W1[(size_t)r * AA + c]) : (unsigned short)0;
}
__global__ void k_cast_w2(const float* __restrict__ W2, unsigned short* __restrict__ W2b) {
  int i = blockIdx.x * 256 + threadIdx.x;
  if (i >= DD * HHP) return;
  int r = i / HHP, c = i % HHP;
  W2b[i] = (c < HH) ? f2bf(W2[(size_t)r * HH + c]) : (unsigned short)0;
}

// ---------------- GEMM A (m97-style, 128x128x32, 4 waves): unchanged --------
__global__ __launch_bounds__(256)
void k_gemm_h(const unsigned short* __restrict__ A, const unsigned short* __restrict__ Bm,
              const float* __restrict__ bias, unsigned short* __restrict__ C) {
  const int K = AAP;
  __shared__ short As[128 * 32];
  __shared__ short Bs[128 * 32];
  int tid = threadIdx.x, wv = tid >> 6, ln = tid & 63;
  int bx = blockIdx.x, by = blockIdx.y;
  int wrow = (wv >> 1) * 64, wcol = (wv & 1) * 64;
  f32x4 acc[4][4] = {};
  size_t ar0 = (size_t)by * 128, br0 = (size_t)bx * 128;
  int soff0 = wv * 1024, soff1 = 4096 + wv * 1024;
  int r0 = soff0 >> 6, r1 = soff1 >> 6;
  int rl = ln >> 2;
  int cbyte = (ln & 3) * 16;
  for (int kt = 0; kt < K; kt += 32) {
    const char* gA0 = (const char*)(A + (ar0 + r0 + rl) * K + kt) + cbyte;
    const char* gA1 = (const char*)(A + (ar0 + r1 + rl) * K + kt) + cbyte;
    const char* gB0 = (const char*)(Bm + (br0 + r0 + rl) * K + kt) + cbyte;
    const char* gB1 = (const char*)(Bm + (br0 + r1 + rl) * K + kt) + cbyte;
    gload_lds16(gA0, &As[soff0 >> 1]);
    gload_lds16(gA1, &As[soff1 >> 1]);
    gload_lds16(gB0, &Bs[soff0 >> 1]);
    gload_lds16(gB1, &Bs[soff1 >> 1]);
    __syncthreads();
    bf16x8 af[4], bfr[4];
#pragma unroll
    for (int i = 0; i < 4; i++)
      af[i] = *(const bf16x8*)&As[(wrow + i * 16 + (ln & 15)) * 32 + (ln >> 4) * 8];
#pragma unroll
    for (int i = 0; i < 4; i++)
      bfr[i] = *(const bf16x8*)&Bs[(wcol + i * 16 + (ln & 15)) * 32 + (ln >> 4) * 8];
#pragma unroll
    for (int m = 0; m < 4; m++)
#pragma unroll
      for (int n = 0; n < 4; n++)
        acc[m][n] = __builtin_amdgcn_mfma_f32_16x16x32_bf16(af[m], bfr[n], acc[m][n], 0, 0, 0);
    __syncthreads();
  }
  int gr0 = by * 128 + wrow + (ln >> 4) * 4;
  int gc0 = bx * 128 + wcol + (ln & 15);
#pragma unroll
  for (int m = 0; m < 4; m++)
#pragma unroll
    for (int r = 0; r < 4; r++) {
      size_t grow = (size_t)(gr0 + m * 16 + r);
#pragma unroll
      for (int n = 0; n < 4; n++) {
        int gcol = gc0 + n * 16;
        float v = acc[m][n][r] + (gcol < HH ? bias[gcol] : 0.f);
        C[grow * HHP + gcol] = f2bf(fmaxf(v, 0.f));
      }
    }
}

// ---------------- GEMM B: 256x256x64 8-wave 4-phase, early-issue + T1 -------
// A = hbuf [MM][HHP] bf16, Bm = W2b [DD][HHP] bf16.
// LDS linear [256][64] bf16 per matrix, double-buffered (128 KiB).
// T2 swizzle: 16B-slot u at row r holds logical slot u^(r&7); pre-swizzled
// global source, same XOR on ds_read (linear gload_lds dest, rule #21).
// T4: all 8 next-tile loads issued at tile top, vmcnt(8) -> youngest load has
// 4 MFMA phases (~700cy) of cover. T1: XCD-chunked bijective blockIdx swizzle.

#define BARRIER asm volatile("s_barrier" ::: "memory")
#define LGKM0   asm volatile("s_waitcnt lgkmcnt(0)" ::: "memory")

#define ISSUE_A(buf, kt, h)                                                        \
  do {                                                                             \
    gload_lds16(aRow + (size_t)((h) * 128) * HHP + (size_t)(kt) * 64,              \
                &LA[buf][(h) * 8192 + ldsw]);                                      \
    gload_lds16(aRow + (size_t)((h) * 128 + 64) * HHP + (size_t)(kt) * 64,         \
                &LA[buf][(h) * 8192 + 4096 + ldsw]);                               \
  } while (0)
#define ISSUE_B(buf, kt, h)                                                        \
  do {                                                                             \
    gload_lds16(bRow + (size_t)((h) * 128) * HHP + (size_t)(kt) * 64,              \
                &LB[buf][(h) * 8192 + ldsw]);                                      \
    gload_lds16(bRow + (size_t)((h) * 128 + 64) * HHP + (size_t)(kt) * 64,         \
                &LB[buf][(h) * 8192 + 4096 + ldsw]);                               \
  } while (0)

#define READ_A(mh)                                                                 \
  do {                                                                             \
    _Pragma("unroll") for (int m = 0; m < 4; m++) {                                \
      int rr = abase + ((mh) * 4 + m) * 1024;                                      \
      av[m][0] = *(const bf16x8*)&LA[cur][rr + axor0];                             \
      av[m][1] = *(const bf16x8*)&LA[cur][rr + axor1];                             \
    }                                                                              \
  } while (0)
#define READ_B(nh)                                                                 \
  do {                                                                             \
    _Pragma("unroll") for (int n = 0; n < 2; n++) {                                \
      int rr = bbase + ((nh) * 2 + n) * 1024;                                      \
      bv[(nh) * 2 + n][0] = *(const bf16x8*)&LB[cur][rr + axor0];                  \
      bv[(nh) * 2 + n][1] = *(const bf16x8*)&LB[cur][rr + axor1];                  \
    }                                                                              \
  } while (0)

#define MFMA1(d, a_, b_) d = __builtin_amdgcn_mfma_f32_16x16x32_bf16(a_, b_, d, 0, 0, 0)
#define MFMA_Q(MB, NB)                                                             \
  do {                                                                             \
    __builtin_amdgcn_s_setprio(1);                                                 \
    _Pragma("unroll") for (int mm = 0; mm < 4; mm++)                               \
    _Pragma("unroll") for (int nn = 0; nn < 2; nn++) {                             \
      MFMA1(acc[(MB) + mm][(NB) + nn], av[mm][0], bv[(NB) + nn][0]);               \
      MFMA1(acc[(MB) + mm][(NB) + nn], av[mm][1], bv[(NB) + nn][1]);               \
    }                                                                              \
    __builtin_amdgcn_s_setprio(0);                                                 \
  } while (0)

__global__ __launch_bounds__(512, 2)
void k_gemm_cls8(const unsigned short* __restrict__ A,
                 const unsigned short* __restrict__ Bm,
                 const float* __restrict__ b2, const float* __restrict__ xf,
                 float* __restrict__ dotb, float* __restrict__ nrm2b) {
  __shared__ short LA[2][16384];
  __shared__ short LB[2][16384];
  const int tid = threadIdx.x, w = tid >> 6, ln = tid & 63;
  const int wr = w >> 2, wc = w & 3;
  const int lr = ln & 15, hi = ln >> 4;
  // T1: XCD-chunked bijective swizzle (nwg=800, 800%8==0)
  const int bid = (int)(blockIdx.x + blockIdx.y * gridDim.x);
  const int lid = (bid & 7) * 100 + (bid >> 3);
  const size_t m0 = (size_t)(lid >> 3) * 256;
  const size_t n0 = (size_t)(lid & 7) * 256;
  // staging: thread covers row = h*128 + q*64 + (tid>>3), 16B-slot u = tid&7.
  // pre-swizzled source column (shorts): ((u ^ (row&7)) * 8); row&7 = (tid>>3)&7.
  const int scol = (((tid & 7) ^ ((tid >> 3) & 7)) << 3);
  const unsigned short* aRow = A + (m0 + (tid >> 3)) * HHP + scol;
  const unsigned short* bRow = Bm + (n0 + (tid >> 3)) * HHP + scol;
  const int ldsw = w * 512;  // wave-uniform LDS base (shorts) within an 8KB chunk

  // fragment read addresses (shorts): (row)*64 + ((slot ^ (row&7))<<3),
  // row = tile_r0 + frag*16 + lr, slot = ks*4 + hi; row&7 == lr&7.
  const int axor0 = ((hi ^ (lr & 7)) << 3);
  const int axor1 = (((4 + hi) ^ (lr & 7)) << 3);
  const int abase = (wr * 128 + lr) * 64;
  const int bbase = (wc * 64 + lr) * 64;

  f32x4 acc[8][4] = {};
  bf16x8 av[4][2], bv[4][2];

  // prologue: stage kt=0 fully into buffer 0 (8 loads/thread)
  ISSUE_A(0, 0, 0); ISSUE_A(0, 0, 1);
  ISSUE_B(0, 0, 0); ISSUE_B(0, 0, 1);

  int cur = 0;
  for (int kt = 0; kt < NKT; ++kt) {
    const int nxt = cur ^ 1;
    if (kt < NKT - 1) {
      // issue ALL next-tile loads before the wait: 8 stay in flight across
      // this K-tile's 4 MFMA phases (deep cover); wait only for buf[cur]'s 8.
      ISSUE_A(nxt, kt + 1, 0); ISSUE_A(nxt, kt + 1, 1);
      ISSUE_B(nxt, kt + 1, 0); ISSUE_B(nxt, kt + 1, 1);
      asm volatile("s_waitcnt vmcnt(8)" ::: "memory");
    } else {
      asm volatile("s_waitcnt vmcnt(0)" ::: "memory");
    }
    BARRIER;  // buf[cur] staged & visible; all waves done reading buf[nxt]
    // ---- phase 0: A mh0 (8 reads) + B n0,n1 (4 reads); MFMA (mh0 x n0n1)
    READ_A(0); READ_B(0);
    BARRIER; LGKM0;
    MFMA_Q(0, 0);
    BARRIER;
    // ---- phase 1: B n2,n3 (4 reads); MFMA (mh0 x n2n3)
    READ_B(1);
    BARRIER; LGKM0;
    MFMA_Q(0, 2);
    BARRIER;
    // ---- phase 2: A mh1 (8 reads); MFMA (mh1 x n2n3)
    READ_A(1);
    BARRIER; LGKM0;
    MFMA_Q(4, 2);
    BARRIER;
    // ---- phase 3: no reads; MFMA (mh1 x n0n1)
    MFMA_Q(4, 0);
    BARRIER;
    cur = nxt;
  }

  // epilogue: cls = relu(acc + b2); accumulate sum(cls^2), sum(cls*x[b]) per row
  const int gc0 = (int)n0 + wc * 64 + lr;
  float bias[4];
#pragma unroll
  for (int n = 0; n < 4; n++) bias[n] = b2[gc0 + n * 16];
  const int grow_base = (int)m0 + wr * 128 + hi * 4;
#pragma unroll
  for (int m = 0; m < 8; m++) {
#pragma unroll
    for (int r = 0; r < 4; r++) {
      int grow = grow_base + m * 16 + r;
      int b = grow / CC;
      const float* xr = xf + (size_t)b * DD;
      float s1 = 0.f, s2 = 0.f;
#pragma unroll
      for (int n = 0; n < 4; n++) {
        float cls = fmaxf(acc[m][n][r] + bias[n], 0.f);
        s1 += cls * cls;
        s2 += cls * xr[gc0 + n * 16];
      }
      s1 += __shfl_xor(s1, 1, 64); s2 += __shfl_xor(s2, 1, 64);
      s1 += __shfl_xor(s1, 2, 64); s2 += __shfl_xor(s2, 2, 64);
      s1 += __shfl_xor(s1, 4, 64); s2 += __shfl_xor(s2, 4, 64);
      s1 += __shfl_xor(s1, 8, 64); s2 += __shfl_xor(s2, 8, 64);
      if (lr == 0) {
        atomicAdd(&nrm2b[grow], s1);
        atomicAdd(&dotb[grow], s2);
      }
    }
  }
}

// ---------------- final: out = scale * (dot / max(||cls||,eps) + bias) ------
__global__ void k_final(const float* __restrict__ dotb, const float* __restrict__ nrm2b,
                        const float* __restrict__ bias_p, const float* __restrict__ scale_cls,
                        float* __restrict__ out) {
  int i = blockIdx.x * 256 + threadIdx.x;
  if (i < MM)
    out[i] = scale_cls[0] * (dotb[i] / fmaxf(sqrtf(nrm2b[i]), 1e-12f) + bias_p[0]);
}

extern "C" void kernel_launch(void* const* d_in, const int* in_sizes, int n_in,
                              void* d_out, int out_size, void* d_ws, size_t ws_size,
                              hipStream_t stream) {
  const float* AttM = (const float*)d_in[0];
  const float* x_in = (const float*)d_in[1];
  const float* Wg = (const float*)d_in[2];
  const float* bg = (const float*)d_in[3];
  const float* W1 = (const float*)d_in[4];
  const float* b1 = (const float*)d_in[5];
  const float* W2 = (const float*)d_in[6];
  const float* b2 = (const float*)d_in[7];
  const float* bias_p = (const float*)d_in[8];
  const float* scale_cls = (const float*)d_in[9];
  float* out = (float*)d_out;

  char* ws = (char*)d_ws;
  size_t off = 0;
  auto alloc = [&](size_t bytes) {
    char* p = ws + off;
    off += (bytes + 255) & ~(size_t)255;
    return p;
  };
  float* xf = (float*)alloc((size_t)BB * DD * 4);
  float* attp = (float*)alloc((size_t)BB * AA * 4);
  unsigned short* comb = (unsigned short*)alloc((size_t)MM * AAP * 2);
  unsigned short* W1b = (unsigned short*)alloc((size_t)HHP * AAP * 2);
  unsigned short* W2b = (unsigned short*)alloc((size_t)DD * HHP * 2);
  unsigned short* hbuf = (unsigned short*)alloc((size_t)MM * HHP * 2);
  float* dotb = (float*)alloc((size_t)MM * 4);
  float* nrm2b = (float*)alloc((size_t)MM * 4);
  (void)ws_size; (void)in_sizes; (void)n_in; (void)out_size;

  // zero the two reduction buffers (contiguous)
  hipMemsetAsync(dotb, 0, (size_t)MM * 4 * 2, stream);

  k_norm<<<BB, 256, 0, stream>>>(x_in, xf);
  k_attn<<<BB, 256, 0, stream>>>(xf, Wg, bg, attp);
  k_cast_w1<<<(HHP * AAP + 255) / 256, 256, 0, stream>>>(W1, W1b);
  k_cast_w2<<<(DD * HHP + 255) / 256, 256, 0, stream>>>(W2, W2b);
  k_comb<<<MM, AAP, 0, stream>>>(attp, AttM, comb);
  k_gemm_h<<<dim3(HHP / 128, MM / 128), 256, 0, stream>>>(comb, W1b, b1, hbuf);
  k_gemm_cls8<<<dim3(DD / 256, MM / 256), 512, 0, stream>>>(hbuf, W2b, b2, xf, dotb, nrm2b);
  k_final<<<(MM + 255) / 256, 256, 0, stream>>>(dotb, nrm2b, bias_p, scale_cls, out);
}

// Round 5
// 327.935 us; speedup vs baseline: 1.6874x; 1.6874x over previous
//
#include <hip/hip_runtime.h>
#include <hip/hip_bf16.h>
#include <math.h>

// Shapes: B=128, C=200, A=312 (pad 320), D=2048, H=1600 (pad 1664), M=B*C=25600
#define BB 128
#define CC 200
#define AA 312
#define AAP 320
#define DD 2048
#define HH 1600
#define HHP 1664
#define MM 25600

typedef __attribute__((ext_vector_type(8))) short bf16x8;
typedef __attribute__((ext_vector_type(4))) float f32x4;

__device__ __forceinline__ unsigned short f2bf(float f) {
  union { float f; unsigned int u; } v; v.f = f;
  unsigned int u = v.u;
  unsigned int r = (u + 0x7fffu + ((u >> 16) & 1u)) >> 16;
  return (unsigned short)r;
}
__device__ __forceinline__ float bf2f(unsigned short b) {
  union { unsigned int u; float f; } v; v.u = ((unsigned int)b) << 16;
  return v.f;
}

__device__ __forceinline__ void gload_lds16(const void* g, void* l) {
  __builtin_amdgcn_global_load_lds(
      (const __attribute__((address_space(1))) unsigned int*)g,
      (__attribute__((address_space(3))) unsigned int*)l, 16, 0, 0);
}

// ---------------- fused: l2norm(x) -> xf ; att' = 1+softmax(relu(x@Wg^T+bg)/5)
__global__ __launch_bounds__(256)
void k_norm_attn(const float* __restrict__ x_in, const unsigned short* __restrict__ Wgb,
                 const float* __restrict__ bg, float* __restrict__ xf,
                 float* __restrict__ attp) {
  int b = blockIdx.x;
  int t = threadIdx.x, wv = t >> 6, ln = t & 63;
  __shared__ float xs[DD];
  __shared__ float sa[AA];
  __shared__ float wsum[4];
  // --- norm ---
  const float4* xi = (const float4*)(x_in + (size_t)b * DD);
  float4 v0 = xi[t], v1 = xi[t + 256];
  float s = v0.x*v0.x + v0.y*v0.y + v0.z*v0.z + v0.w*v0.w
          + v1.x*v1.x + v1.y*v1.y + v1.z*v1.z + v1.w*v1.w;
  for (int off = 32; off; off >>= 1) s += __shfl_xor(s, off, 64);
  if (ln == 0) wsum[wv] = s;
  __syncthreads();
  float sc = 1.f / fmaxf(sqrtf(wsum[0] + wsum[1] + wsum[2] + wsum[3]), 1e-12f);
  v0.x *= sc; v0.y *= sc; v0.z *= sc; v0.w *= sc;
  v1.x *= sc; v1.y *= sc; v1.z *= sc; v1.w *= sc;
  float4* xo = (float4*)(xf + (size_t)b * DD);
  xo[t] = v0; xo[t + 256] = v1;
  ((float4*)xs)[t] = v0; ((float4*)xs)[t + 256] = v1;
  __syncthreads();
  // --- attention scores (Wg in bf16) ---
  for (int a = wv; a < AA; a += 4) {
    const bf16x8* wrow = (const bf16x8*)(Wgb + (size_t)a * DD);
    float acc = 0.f;
#pragma unroll
    for (int j = 0; j < 4; j++) {
      bf16x8 w = wrow[j * 64 + ln];
      const float* xv = &xs[(j * 64 + ln) * 8];
#pragma unroll
      for (int e = 0; e < 8; e++) acc += bf2f((unsigned short)w[e]) * xv[e];
    }
    for (int off = 32; off; off >>= 1) acc += __shfl_xor(acc, off, 64);
    if (ln == 0) sa[a] = fmaxf(acc + bg[a], 0.f) * 0.2f;  // /TMP, TMP=5
  }
  __syncthreads();
  if (wv == 0) {
    float mx = -1e30f;
    for (int i = ln; i < AA; i += 64) mx = fmaxf(mx, sa[i]);
    for (int off = 32; off; off >>= 1) mx = fmaxf(mx, __shfl_xor(mx, off, 64));
    float ev[5]; float sm = 0.f;
#pragma unroll
    for (int k = 0; k < 5; k++) {
      int i = ln + k * 64;
      ev[k] = (i < AA) ? expf(sa[i] - mx) : 0.f;
      sm += ev[k];
    }
    for (int off = 32; off; off >>= 1) sm += __shfl_xor(sm, off, 64);
    float inv = 1.f / sm;
#pragma unroll
    for (int k = 0; k < 5; k++) {
      int i = ln + k * 64;
      if (i < AA) attp[(size_t)b * AA + i] = 1.f + ev[k] * inv;
    }
  }
}

// ---------------- comb[m][a] = att'[b][a]*AttM[c][a] (bf16, K-pad to 320) ---
__global__ void k_comb(const float* __restrict__ attp, const float* __restrict__ AttM,
                       unsigned short* __restrict__ comb) {
  int m = blockIdx.x;
  int a = threadIdx.x;
  int b = m / CC, c = m % CC;
  unsigned short v = 0;
  if (a < AA) v = f2bf(attp[(size_t)b * AA + a] * AttM[(size_t)c * AA + a]);
  comb[(size_t)m * AAP + a] = v;
}

// ---------------- fused weight casts (padded, zero-filled) ------------------
#define R1SZ (HHP * AAP)
#define R2SZ (DD * HHP)
#define R3SZ (AA * DD)
__global__ void k_cast_all(const float* __restrict__ W1, const float* __restrict__ W2,
                           const float* __restrict__ Wg, unsigned short* __restrict__ W1b,
                           unsigned short* __restrict__ W2b, unsigned short* __restrict__ Wgb) {
  int i = blockIdx.x * 256 + threadIdx.x;
  if (i < R1SZ) {
    int r = i / AAP, c = i % AAP;
    W1b[i] = (r < HH && c < AA) ? f2bf(W1[(size_t)r * AA + c]) : (unsigned short)0;
  } else if (i < R1SZ + R2SZ) {
    int j = i - R1SZ;
    int r = j / HHP, c = j % HHP;
    W2b[j] = (c < HH) ? f2bf(W2[(size_t)r * HH + c]) : (unsigned short)0;
  } else if (i < R1SZ + R2SZ + R3SZ) {
    int j = i - R1SZ - R2SZ;
    Wgb[j] = f2bf(Wg[j]);
  }
}

// ---------------- 2-phase 128x128xBK=64 GEMM core (m97 + T2 swizzle) --------
// A row-major [M,KD] bf16, B row-major [N,KD] bf16 (B^T gemm). 256 thr, 4 waves.
// LDS [128][64] per matrix, single-buffered (32 KB -> 4-5 blocks/CU).
// Swizzle: 16B-slot u at row r holds logical u^(r&7); pre-swizzled global src,
// same XOR on ds_read (linear gload_lds dest). Verified in R2/R4 (conflicts=0).
template <int KD, int NT>
__device__ __forceinline__ void gemm_core(const unsigned short* __restrict__ A,
                                          const unsigned short* __restrict__ Bm,
                                          short* As, short* Bs, f32x4 (&acc)[4][4],
                                          size_t ar0, size_t br0, int tid, int w, int ln) {
  const int scol = (((tid & 7) ^ ((tid >> 3) & 7)) << 3);
  const unsigned short* aP = A + (ar0 + (tid >> 3)) * KD + scol;
  const unsigned short* bP = Bm + (br0 + (tid >> 3)) * KD + scol;
  const int lr = ln & 15, hi = ln >> 4;
  const int axor0 = ((hi ^ (lr & 7)) << 3);
  const int axor1 = (((4 + hi) ^ (lr & 7)) << 3);
  const int wrow = (w >> 1) * 64, wcol = (w & 1) * 64;
  const int abase = (wrow + lr) * 64, bbase = (wcol + lr) * 64;
  for (int kt = 0; kt < NT; ++kt) {
#pragma unroll
    for (int p = 0; p < 4; p++) {
      gload_lds16(aP + (size_t)(p * 32) * KD + kt * 64, &As[p * 2048 + tid * 8]);
      gload_lds16(bP + (size_t)(p * 32) * KD + kt * 64, &Bs[p * 2048 + tid * 8]);
    }
    __syncthreads();
    bf16x8 av[4][2], bv[4][2];
#pragma unroll
    for (int i = 0; i < 4; i++) {
      av[i][0] = *(const bf16x8*)&As[abase + i * 1024 + axor0];
      av[i][1] = *(const bf16x8*)&As[abase + i * 1024 + axor1];
    }
#pragma unroll
    for (int i = 0; i < 4; i++) {
      bv[i][0] = *(const bf16x8*)&Bs[bbase + i * 1024 + axor0];
      bv[i][1] = *(const bf16x8*)&Bs[bbase + i * 1024 + axor1];
    }
#pragma unroll
    for (int m = 0; m < 4; m++)
#pragma unroll
      for (int n = 0; n < 4; n++) {
        acc[m][n] = __builtin_amdgcn_mfma_f32_16x16x32_bf16(av[m][0], bv[n][0], acc[m][n], 0, 0, 0);
        acc[m][n] = __builtin_amdgcn_mfma_f32_16x16x32_bf16(av[m][1], bv[n][1], acc[m][n], 0, 0, 0);
      }
    __syncthreads();
  }
}

// GEMM A: h = relu(comb @ W1b^T + b1) -> bf16 [MM, HHP]
__global__ __launch_bounds__(256, 4)
void k_gemm_h(const unsigned short* __restrict__ A, const unsigned short* __restrict__ Bm,
              const float* __restrict__ bias, unsigned short* __restrict__ C) {
  __shared__ short As[128 * 64];
  __shared__ short Bs[128 * 64];
  int tid = threadIdx.x, w = tid >> 6, ln = tid & 63;
  f32x4 acc[4][4] = {};
  gemm_core<AAP, AAP / 64>(A, Bm, As, Bs, acc, (size_t)blockIdx.y * 128,
                           (size_t)blockIdx.x * 128, tid, w, ln);
  int wrow = (w >> 1) * 64, wcol = (w & 1) * 64;
  int gr0 = blockIdx.y * 128 + wrow + (ln >> 4) * 4;
  int gc0 = blockIdx.x * 128 + wcol + (ln & 15);
#pragma unroll
  for (int m = 0; m < 4; m++)
#pragma unroll
    for (int r = 0; r < 4; r++) {
      size_t grow = (size_t)(gr0 + m * 16 + r);
#pragma unroll
      for (int n = 0; n < 4; n++) {
        int gcol = gc0 + n * 16;
        float v = acc[m][n][r] + (gcol < HH ? bias[gcol] : 0.f);
        C[grow * HHP + gcol] = f2bf(fmaxf(v, 0.f));
      }
    }
}

// GEMM B: cls = relu(h @ W2b^T + b2); accumulate sum(cls^2), sum(cls*x[b])
__global__ __launch_bounds__(256, 4)
void k_gemm_cls(const unsigned short* __restrict__ A, const unsigned short* __restrict__ Bm,
                const float* __restrict__ b2, const float* __restrict__ xf,
                float* __restrict__ dotb, float* __restrict__ nrm2b) {
  __shared__ short As[128 * 64];
  __shared__ short Bs[128 * 64];
  int tid = threadIdx.x, w = tid >> 6, ln = tid & 63;
  f32x4 acc[4][4] = {};
  gemm_core<HHP, HHP / 64>(A, Bm, As, Bs, acc, (size_t)blockIdx.y * 128,
                           (size_t)blockIdx.x * 128, tid, w, ln);
  int wrow = (w >> 1) * 64, wcol = (w & 1) * 64;
  int gr0 = blockIdx.y * 128 + wrow + (ln >> 4) * 4;
  int gc0 = blockIdx.x * 128 + wcol + (ln & 15);
  float bias[4];
#pragma unroll
  for (int n = 0; n < 4; n++) bias[n] = b2[gc0 + n * 16];
#pragma unroll
  for (int m = 0; m < 4; m++)
#pragma unroll
    for (int r = 0; r < 4; r++) {
      int grow = gr0 + m * 16 + r;
      int b = grow / CC;
      const float* xr = xf + (size_t)b * DD;
      float s1 = 0.f, s2 = 0.f;
#pragma unroll
      for (int n = 0; n < 4; n++) {
        float cls = fmaxf(acc[m][n][r] + bias[n], 0.f);
        s1 += cls * cls;
        s2 += cls * xr[gc0 + n * 16];
      }
      s1 += __shfl_xor(s1, 1, 64); s2 += __shfl_xor(s2, 1, 64);
      s1 += __shfl_xor(s1, 2, 64); s2 += __shfl_xor(s2, 2, 64);
      s1 += __shfl_xor(s1, 4, 64); s2 += __shfl_xor(s2, 4, 64);
      s1 += __shfl_xor(s1, 8, 64); s2 += __shfl_xor(s2, 8, 64);
      if ((ln & 15) == 0) {
        atomicAdd(&nrm2b[grow], s1);
        atomicAdd(&dotb[grow], s2);
      }
    }
}

// ---------------- final: out = scale * (dot / max(||cls||,eps) + bias) ------
__global__ void k_final(const float* __restrict__ dotb, const float* __restrict__ nrm2b,
                        const float* __restrict__ bias_p, const float* __restrict__ scale_cls,
                        float* __restrict__ out) {
  int i = blockIdx.x * 256 + threadIdx.x;
  if (i < MM)
    out[i] = scale_cls[0] * (dotb[i] / fmaxf(sqrtf(nrm2b[i]), 1e-12f) + bias_p[0]);
}

extern "C" void kernel_launch(void* const* d_in, const int* in_sizes, int n_in,
                              void* d_out, int out_size, void* d_ws, size_t ws_size,
                              hipStream_t stream) {
  const float* AttM = (const float*)d_in[0];
  const float* x_in = (const float*)d_in[1];
  const float* Wg = (const float*)d_in[2];
  const float* bg = (const float*)d_in[3];
  const float* W1 = (const float*)d_in[4];
  const float* b1 = (const float*)d_in[5];
  const float* W2 = (const float*)d_in[6];
  const float* b2 = (const float*)d_in[7];
  const float* bias_p = (const float*)d_in[8];
  const float* scale_cls = (const float*)d_in[9];
  float* out = (float*)d_out;

  char* ws = (char*)d_ws;
  size_t off = 0;
  auto alloc = [&](size_t bytes) {
    char* p = ws + off;
    off += (bytes + 255) & ~(size_t)255;
    return p;
  };
  float* xf = (float*)alloc((size_t)BB * DD * 4);
  float* attp = (float*)alloc((size_t)BB * AA * 4);
  unsigned short* comb = (unsigned short*)alloc((size_t)MM * AAP * 2);
  unsigned short* W1b = (unsigned short*)alloc((size_t)HHP * AAP * 2);
  unsigned short* W2b = (unsigned short*)alloc((size_t)DD * HHP * 2);
  unsigned short* Wgb = (unsigned short*)alloc((size_t)AA * DD * 2);
  unsigned short* hbuf = (unsigned short*)alloc((size_t)MM * HHP * 2);
  float* dotb = (float*)alloc((size_t)MM * 4);
  float* nrm2b = (float*)alloc((size_t)MM * 4);
  (void)ws_size; (void)in_sizes; (void)n_in; (void)out_size;

  // zero the two reduction buffers (contiguous)
  hipMemsetAsync(dotb, 0, (size_t)MM * 4 * 2, stream);

  k_cast_all<<<(R1SZ + R2SZ + R3SZ + 255) / 256, 256, 0, stream>>>(W1, W2, Wg, W1b, W2b, Wgb);
  k_norm_attn<<<BB, 256, 0, stream>>>(x_in, Wgb, bg, xf, attp);
  k_comb<<<MM, AAP, 0, stream>>>(attp, AttM, comb);
  k_gemm_h<<<dim3(HHP / 128, MM / 128), 256, 0, stream>>>(comb, W1b, b1, hbuf);
  k_gemm_cls<<<dim3(DD / 128, MM / 128), 256, 0, stream>>>(hbuf, W2b, b2, xf, dotb, nrm2b);
  k_final<<<(MM + 255) / 256, 256, 0, stream>>>(dotb, nrm2b, bias_p, scale_cls, out);
}

// Round 6
// 315.419 us; speedup vs baseline: 1.7544x; 1.0397x over previous
//
#include <hip/hip_runtime.h>
#include <hip/hip_bf16.h>
#include <math.h>

// Shapes: B=128, C=200, A=312 (pad 320), D=2048, H=1600, M=B*C=25600
#define BB 128
#define CC 200
#define AA 312
#define AAP 320
#define DD 2048
#define HH 1600
#define HHP 1664   // W1b padded rows (gemm_h N-dim), h cols >=1600 discarded
#define MM 25600

typedef __attribute__((ext_vector_type(8))) short bf16x8;
typedef __attribute__((ext_vector_type(4))) float f32x4;
typedef __attribute__((ext_vector_type(4))) unsigned short u16x4;

__device__ __forceinline__ unsigned short f2bf(float f) {
  union { float f; unsigned int u; } v; v.f = f;
  unsigned int u = v.u;
  unsigned int r = (u + 0x7fffu + ((u >> 16) & 1u)) >> 16;
  return (unsigned short)r;
}
__device__ __forceinline__ float bf2f(unsigned short b) {
  union { unsigned int u; float f; } v; v.u = ((unsigned int)b) << 16;
  return v.f;
}

__device__ __forceinline__ void gload_lds16(const void* g, void* l) {
  __builtin_amdgcn_global_load_lds(
      (const __attribute__((address_space(1))) unsigned int*)g,
      (__attribute__((address_space(3))) unsigned int*)l, 16, 0, 0);
}

// ---- fused: l2norm(x)->xf ; att'=1+softmax(relu(x@Wg^T+bg)/5); comb write ---
__global__ __launch_bounds__(256)
void k_norm_attn(const float* __restrict__ x_in, const unsigned short* __restrict__ Wgb,
                 const float* __restrict__ bg, const float* __restrict__ AttM,
                 float* __restrict__ xf, unsigned short* __restrict__ comb) {
  int b = blockIdx.x;
  int t = threadIdx.x, wv = t >> 6, ln = t & 63;
  __shared__ float xs[DD];
  __shared__ float satt[AAP];
  __shared__ float wsum[4];
  if (t < AAP - AA) satt[AA + t] = 0.f;  // zero K-pad cols 312..319
  // --- norm ---
  const float4* xi = (const float4*)(x_in + (size_t)b * DD);
  float4 v0 = xi[t], v1 = xi[t + 256];
  float s = v0.x*v0.x + v0.y*v0.y + v0.z*v0.z + v0.w*v0.w
          + v1.x*v1.x + v1.y*v1.y + v1.z*v1.z + v1.w*v1.w;
  for (int off = 32; off; off >>= 1) s += __shfl_xor(s, off, 64);
  if (ln == 0) wsum[wv] = s;
  __syncthreads();
  float sc = 1.f / fmaxf(sqrtf(wsum[0] + wsum[1] + wsum[2] + wsum[3]), 1e-12f);
  v0.x *= sc; v0.y *= sc; v0.z *= sc; v0.w *= sc;
  v1.x *= sc; v1.y *= sc; v1.z *= sc; v1.w *= sc;
  float4* xo = (float4*)(xf + (size_t)b * DD);
  xo[t] = v0; xo[t + 256] = v1;
  ((float4*)xs)[t] = v0; ((float4*)xs)[t + 256] = v1;
  __syncthreads();
  // --- attention scores (Wg bf16) ---
  for (int a = wv; a < AA; a += 4) {
    const bf16x8* wrow = (const bf16x8*)(Wgb + (size_t)a * DD);
    float acc = 0.f;
#pragma unroll
    for (int j = 0; j < 4; j++) {
      bf16x8 w = wrow[j * 64 + ln];
      const float* xv = &xs[(j * 64 + ln) * 8];
#pragma unroll
      for (int e = 0; e < 8; e++) acc += bf2f((unsigned short)w[e]) * xv[e];
    }
    for (int off = 32; off; off >>= 1) acc += __shfl_xor(acc, off, 64);
    if (ln == 0) satt[a] = fmaxf(acc + bg[a], 0.f) * 0.2f;  // /TMP, TMP=5
  }
  __syncthreads();
  // --- softmax (+1) in wave 0 ---
  if (wv == 0) {
    float mx = -1e30f;
    for (int i = ln; i < AA; i += 64) mx = fmaxf(mx, satt[i]);
    for (int off = 32; off; off >>= 1) mx = fmaxf(mx, __shfl_xor(mx, off, 64));
    float ev[5]; float sm = 0.f;
#pragma unroll
    for (int k = 0; k < 5; k++) {
      int i = ln + k * 64;
      ev[k] = (i < AA) ? expf(satt[i] - mx) : 0.f;
      sm += ev[k];
    }
    for (int off = 32; off; off >>= 1) sm += __shfl_xor(sm, off, 64);
    float inv = 1.f / sm;
#pragma unroll
    for (int k = 0; k < 5; k++) {
      int i = ln + k * 64;
      if (i < AA) satt[i] = 1.f + ev[k] * inv;
    }
  }
  __syncthreads();
  // --- comb[m][a] = satt[a]*AttM[c][a], m = b*CC+c, bf16, 8 elems/item ---
  const size_t mbase = (size_t)b * CC;
  for (int idx = t; idx < CC * 40; idx += 256) {
    int c = idx / 40, j = idx - c * 40;
    bf16x8 v = {};
    if (j < 39) {  // j=39 covers a=312..319: all pad -> zeros
      const float4* ap = (const float4*)(AttM + (size_t)c * AA + j * 8);
      float4 p0 = ap[0], p1 = ap[1];
      const float* sv = &satt[j * 8];
      v[0] = (short)f2bf(p0.x * sv[0]); v[1] = (short)f2bf(p0.y * sv[1]);
      v[2] = (short)f2bf(p0.z * sv[2]); v[3] = (short)f2bf(p0.w * sv[3]);
      v[4] = (short)f2bf(p1.x * sv[4]); v[5] = (short)f2bf(p1.y * sv[5]);
      v[6] = (short)f2bf(p1.z * sv[6]); v[7] = (short)f2bf(p1.w * sv[7]);
    }
    *(bf16x8*)(comb + (mbase + c) * AAP + j * 8) = v;
  }
}

// ---- fused weight casts, 4 elems/thread -----------------------------------
#define R1SZ (HHP * AAP)   // W1b padded [1664][320]
#define R2SZ (DD * HH)     // W2b flat [2048][1600]
#define R3SZ (AA * DD)     // Wgb flat
__global__ void k_cast_all(const float* __restrict__ W1, const float* __restrict__ W2,
                           const float* __restrict__ Wg, unsigned short* __restrict__ W1b,
                           unsigned short* __restrict__ W2b, unsigned short* __restrict__ Wgb) {
  int i = (blockIdx.x * 256 + threadIdx.x) * 4;
  if (i < R1SZ) {
    int r = i / AAP, c = i - r * AAP;
    u16x4 o = {};
    if (r < HH && c < AA) {  // c%4==0, c<312 => c<=308, c+3<=311 valid
      float4 f = *(const float4*)(W1 + (size_t)r * AA + c);
      o[0] = f2bf(f.x); o[1] = f2bf(f.y); o[2] = f2bf(f.z); o[3] = f2bf(f.w);
    }
    *(u16x4*)(W1b + i) = o;
  } else if (i < R1SZ + R2SZ) {
    int j = i - R1SZ;
    float4 f = *(const float4*)(W2 + j);
    u16x4 o; o[0] = f2bf(f.x); o[1] = f2bf(f.y); o[2] = f2bf(f.z); o[3] = f2bf(f.w);
    *(u16x4*)(W2b + j) = o;
  } else if (i < R1SZ + R2SZ + R3SZ) {
    int j = i - R1SZ - R2SZ;
    float4 f = *(const float4*)(Wg + j);
    u16x4 o; o[0] = f2bf(f.x); o[1] = f2bf(f.y); o[2] = f2bf(f.z); o[3] = f2bf(f.w);
    *(u16x4*)(Wgb + j) = o;
  }
}

// ---- 2-phase 128x128xBK=64 GEMM core (m97 + T2 swizzle), unchanged ---------
template <int KD, int NT>
__device__ __forceinline__ void gemm_core(const unsigned short* __restrict__ A,
                                          const unsigned short* __restrict__ Bm,
                                          short* As, short* Bs, f32x4 (&acc)[4][4],
                                          size_t ar0, size_t br0, int tid, int w, int ln) {
  const int scol = (((tid & 7) ^ ((tid >> 3) & 7)) << 3);
  const unsigned short* aP = A + (ar0 + (tid >> 3)) * KD + scol;
  const unsigned short* bP = Bm + (br0 + (tid >> 3)) * KD + scol;
  const int lr = ln & 15, hi = ln >> 4;
  const int axor0 = ((hi ^ (lr & 7)) << 3);
  const int axor1 = (((4 + hi) ^ (lr & 7)) << 3);
  const int wrow = (w >> 1) * 64, wcol = (w & 1) * 64;
  const int abase = (wrow + lr) * 64, bbase = (wcol + lr) * 64;
  for (int kt = 0; kt < NT; ++kt) {
#pragma unroll
    for (int p = 0; p < 4; p++) {
      gload_lds16(aP + (size_t)(p * 32) * KD + kt * 64, &As[p * 2048 + tid * 8]);
      gload_lds16(bP + (size_t)(p * 32) * KD + kt * 64, &Bs[p * 2048 + tid * 8]);
    }
    __syncthreads();
    bf16x8 av[4][2], bv[4][2];
#pragma unroll
    for (int i = 0; i < 4; i++) {
      av[i][0] = *(const bf16x8*)&As[abase + i * 1024 + axor0];
      av[i][1] = *(const bf16x8*)&As[abase + i * 1024 + axor1];
    }
#pragma unroll
    for (int i = 0; i < 4; i++) {
      bv[i][0] = *(const bf16x8*)&Bs[bbase + i * 1024 + axor0];
      bv[i][1] = *(const bf16x8*)&Bs[bbase + i * 1024 + axor1];
    }
#pragma unroll
    for (int m = 0; m < 4; m++)
#pragma unroll
      for (int n = 0; n < 4; n++) {
        acc[m][n] = __builtin_amdgcn_mfma_f32_16x16x32_bf16(av[m][0], bv[n][0], acc[m][n], 0, 0, 0);
        acc[m][n] = __builtin_amdgcn_mfma_f32_16x16x32_bf16(av[m][1], bv[n][1], acc[m][n], 0, 0, 0);
      }
    __syncthreads();
  }
}

// GEMM A: h = relu(comb @ W1b^T + b1) -> bf16 [MM][HH], cols >=HH discarded
__global__ __launch_bounds__(256, 4)
void k_gemm_h(const unsigned short* __restrict__ A, const unsigned short* __restrict__ Bm,
              const float* __restrict__ bias, unsigned short* __restrict__ C) {
  __shared__ short As[128 * 64];
  __shared__ short Bs[128 * 64];
  int tid = threadIdx.x, w = tid >> 6, ln = tid & 63;
  // T1: bijective XCD swizzle, nwg=2600=8*325
  int bid = blockIdx.x + blockIdx.y * gridDim.x;
  int lid = (bid & 7) * 325 + (bid >> 3);
  int bx = lid % 13, by = lid / 13;
  f32x4 acc[4][4] = {};
  gemm_core<AAP, AAP / 64>(A, Bm, As, Bs, acc, (size_t)by * 128,
                           (size_t)bx * 128, tid, w, ln);
  int wrow = (w >> 1) * 64, wcol = (w & 1) * 64;
  int gr0 = by * 128 + wrow + (ln >> 4) * 4;
  int gc0 = bx * 128 + wcol + (ln & 15);
#pragma unroll
  for (int m = 0; m < 4; m++)
#pragma unroll
    for (int r = 0; r < 4; r++) {
      size_t grow = (size_t)(gr0 + m * 16 + r);
#pragma unroll
      for (int n = 0; n < 4; n++) {
        int gcol = gc0 + n * 16;
        if (gcol < HH) {
          float v = acc[m][n][r] + bias[gcol];
          C[grow * HH + gcol] = f2bf(fmaxf(v, 0.f));
        }
      }
    }
}

// GEMM B: cls = relu(h @ W2b^T + b2); accumulate sum(cls^2), sum(cls*x[b])
__global__ __launch_bounds__(256, 4)
void k_gemm_cls(const unsigned short* __restrict__ A, const unsigned short* __restrict__ Bm,
                const float* __restrict__ b2, const float* __restrict__ xf,
                float* __restrict__ dotb, float* __restrict__ nrm2b) {
  __shared__ short As[128 * 64];
  __shared__ short Bs[128 * 64];
  int tid = threadIdx.x, w = tid >> 6, ln = tid & 63;
  // T1: bijective XCD swizzle, nwg=3200=8*400; n-major within XCD chunk
  int bid = blockIdx.x + blockIdx.y * gridDim.x;
  int lid = (bid & 7) * 400 + (bid >> 3);
  int bx = lid & 15, by = lid >> 4;
  f32x4 acc[4][4] = {};
  gemm_core<HH, HH / 64>(A, Bm, As, Bs, acc, (size_t)by * 128,
                         (size_t)bx * 128, tid, w, ln);
  int wrow = (w >> 1) * 64, wcol = (w & 1) * 64;
  int gr0 = by * 128 + wrow + (ln >> 4) * 4;
  int gc0 = bx * 128 + wcol + (ln & 15);
  float bias[4];
#pragma unroll
  for (int n = 0; n < 4; n++) bias[n] = b2[gc0 + n * 16];
#pragma unroll
  for (int m = 0; m < 4; m++)
#pragma unroll
    for (int r = 0; r < 4; r++) {
      int grow = gr0 + m * 16 + r;
      int b = grow / CC;
      const float* xr = xf + (size_t)b * DD;
      float s1 = 0.f, s2 = 0.f;
#pragma unroll
      for (int n = 0; n < 4; n++) {
        float cls = fmaxf(acc[m][n][r] + bias[n], 0.f);
        s1 += cls * cls;
        s2 += cls * xr[gc0 + n * 16];
      }
      s1 += __shfl_xor(s1, 1, 64); s2 += __shfl_xor(s2, 1, 64);
      s1 += __shfl_xor(s1, 2, 64); s2 += __shfl_xor(s2, 2, 64);
      s1 += __shfl_xor(s1, 4, 64); s2 += __shfl_xor(s2, 4, 64);
      s1 += __shfl_xor(s1, 8, 64); s2 += __shfl_xor(s2, 8, 64);
      if ((ln & 15) == 0) {
        atomicAdd(&nrm2b[grow], s1);
        atomicAdd(&dotb[grow], s2);
      }
    }
}

// ---- final: out = scale * (dot / max(||cls||,eps) + bias) ------------------
__global__ void k_final(const float* __restrict__ dotb, const float* __restrict__ nrm2b,
                        const float* __restrict__ bias_p, const float* __restrict__ scale_cls,
                        float* __restrict__ out) {
  int i = blockIdx.x * 256 + threadIdx.x;
  if (i < MM)
    out[i] = scale_cls[0] * (dotb[i] / fmaxf(sqrtf(nrm2b[i]), 1e-12f) + bias_p[0]);
}

extern "C" void kernel_launch(void* const* d_in, const int* in_sizes, int n_in,
                              void* d_out, int out_size, void* d_ws, size_t ws_size,
                              hipStream_t stream) {
  const float* AttM = (const float*)d_in[0];
  const float* x_in = (const float*)d_in[1];
  const float* Wg = (const float*)d_in[2];
  const float* bg = (const float*)d_in[3];
  const float* W1 = (const float*)d_in[4];
  const float* b1 = (const float*)d_in[5];
  const float* W2 = (const float*)d_in[6];
  const float* b2 = (const float*)d_in[7];
  const float* bias_p = (const float*)d_in[8];
  const float* scale_cls = (const float*)d_in[9];
  float* out = (float*)d_out;

  char* ws = (char*)d_ws;
  size_t off = 0;
  auto alloc = [&](size_t bytes) {
    char* p = ws + off;
    off += (bytes + 255) & ~(size_t)255;
    return p;
  };
  float* xf = (float*)alloc((size_t)BB * DD * 4);
  unsigned short* comb = (unsigned short*)alloc((size_t)MM * AAP * 2);
  unsigned short* W1b = (unsigned short*)alloc((size_t)R1SZ * 2);
  unsigned short* W2b = (unsigned short*)alloc((size_t)R2SZ * 2);
  unsigned short* Wgb = (unsigned short*)alloc((size_t)R3SZ * 2);
  unsigned short* hbuf = (unsigned short*)alloc((size_t)MM * HH * 2);
  float* dotb = (float*)alloc((size_t)MM * 4);
  float* nrm2b = (float*)alloc((size_t)MM * 4);
  (void)ws_size; (void)in_sizes; (void)n_in; (void)out_size;

  // zero the two reduction buffers (contiguous)
  hipMemsetAsync(dotb, 0, (size_t)MM * 4 * 2, stream);

  k_cast_all<<<((R1SZ + R2SZ + R3SZ) / 4 + 255) / 256, 256, 0, stream>>>(W1, W2, Wg, W1b, W2b, Wgb);
  k_norm_attn<<<BB, 256, 0, stream>>>(x_in, Wgb, bg, AttM, xf, comb);
  k_gemm_h<<<dim3(13, MM / 128), 256, 0, stream>>>(comb, W1b, b1, hbuf);
  k_gemm_cls<<<dim3(DD / 128, MM / 128), 256, 0, stream>>>(hbuf, W2b, b2, xf, dotb, nrm2b);
  k_final<<<(MM + 255) / 256, 256, 0, stream>>>(dotb, nrm2b, bias_p, scale_cls, out);
}